// Round 15
// baseline (363.109 us; speedup 1.0000x reference)
//
#include <hip/hip_runtime.h>
#include <hip/hip_bf16.h>
#include <math.h>

#define N_NODES 50000
#define N_EDGES 800000
#define HID 64
#define NBK 196          // buckets of 256 nodes
#define EPB 4096         // edges per hist/scatter block
#define SB  ((N_EDGES + EPB - 1) / EPB)   // 196
#define FLAT (NBK * SB)  // 38416 flattened (bucket-major) histogram entries

// fused prep grid partition
#define LN0_BLKS   6250
#define HIST_BLKS  SB
#define WP0_BLKS   32    // 16*1*512 / 256
#define WP12_BLKS  64    // 16*2*512 / 256
#define PREP_BLKS  (LN0_BLKS + HIST_BLKS + WP0_BLKS + 2 * WP12_BLKS)

typedef __attribute__((ext_vector_type(8))) short short8;
typedef __attribute__((ext_vector_type(4))) float float4v;

__device__ __forceinline__ unsigned short f32_to_bf16_rne(float f) {
    unsigned int u = __float_as_uint(f);
    unsigned int r = u + 0x7fffu + ((u >> 16) & 1u);
    return (unsigned short)(r >> 16);
}

// ---------------------------------------------------------------------------
// Device helpers for the fused prep kernel.
__device__ __forceinline__ void ln0_body(int b, int t,
        const float* __restrict__ x, const float* __restrict__ g,
        const float* __restrict__ bb, float* __restrict__ h0) {
    int lane = t & 63;
    int n = b * 8 + (t >> 6) * 2 + (lane >> 5);
    int c = lane & 31;
    float v = x[n * 32 + c];
    float s = v;
    #pragma unroll
    for (int off = 1; off < 32; off <<= 1) s += __shfl_xor(s, off);
    float mu = s * (1.0f / 32.0f);
    float d = v - mu;
    float vs = d * d;
    #pragma unroll
    for (int off = 1; off < 32; off <<= 1) vs += __shfl_xor(vs, off);
    float var = vs * (1.0f / 32.0f);
    h0[n * 32 + c] = d * rsqrtf(var + 1e-5f) * g[c] + bb[c];
}

__device__ __forceinline__ void wprep_body(int idx, int KS,
        const float* __restrict__ Wq, const float* __restrict__ Wk,
        const float* __restrict__ Wv, const float* __restrict__ Ws,
        unsigned short* __restrict__ Wp) {
    int j = idx & 7;
    int lane = (idx >> 3) & 63;
    int ts = idx >> 9;            // tile*KS + s
    int s = ts % KS;
    int tile = ts / KS;
    int which = tile >> 2;
    int slice = tile & 3;
    int k = s * 32 + ((lane >> 4) * 8) + j;
    int col = slice * 16 + (lane & 15);
    const float* W = (which == 0) ? Wq : (which == 1) ? Wk : (which == 2) ? Wv : Ws;
    Wp[idx] = f32_to_bf16_rne(W[k * 64 + col]);
}

// ---------------------------------------------------------------------------
// Fused prep: ln0 + per-block bucket histogram + 3x weight pack.
__global__ __launch_bounds__(256) void prep_kernel(
        const float* __restrict__ x, const float* __restrict__ ln0g,
        const float* __restrict__ ln0b, float* __restrict__ h0,
        const int* __restrict__ dst, int* __restrict__ ghist,
        const float* __restrict__ Wq0, const float* __restrict__ Wk0,
        const float* __restrict__ Wv0, const float* __restrict__ Ws0,
        unsigned short* __restrict__ Wp0,
        const float* __restrict__ Wq1, const float* __restrict__ Wk1,
        const float* __restrict__ Wv1, const float* __restrict__ Ws1,
        unsigned short* __restrict__ Wp1,
        const float* __restrict__ Wq2, const float* __restrict__ Wk2,
        const float* __restrict__ Wv2, const float* __restrict__ Ws2,
        unsigned short* __restrict__ Wp2) {
    __shared__ int hist[NBK];
    int b = blockIdx.x;
    int t = threadIdx.x;
    if (b < LN0_BLKS) {
        ln0_body(b, t, x, ln0g, ln0b, h0);
    } else if (b < LN0_BLKS + HIST_BLKS) {
        int i = b - LN0_BLKS;
        for (int k = t; k < NBK; k += 256) hist[k] = 0;
        __syncthreads();
        int e0 = i * EPB;
        #pragma unroll
        for (int r = 0; r < EPB / 256; r++) {
            int e = e0 + r * 256 + t;
            if (e < N_EDGES) atomicAdd(&hist[dst[e] >> 8], 1);
        }
        __syncthreads();
        for (int k = t; k < NBK; k += 256) ghist[k * SB + i] = hist[k];
    } else if (b < LN0_BLKS + HIST_BLKS + WP0_BLKS) {
        int idx = (b - LN0_BLKS - HIST_BLKS) * 256 + t;
        wprep_body(idx, 1, Wq0, Wk0, Wv0, Ws0, Wp0);
    } else if (b < LN0_BLKS + HIST_BLKS + WP0_BLKS + WP12_BLKS) {
        int idx = (b - LN0_BLKS - HIST_BLKS - WP0_BLKS) * 256 + t;
        wprep_body(idx, 2, Wq1, Wk1, Wv1, Ws1, Wp1);
    } else {
        int idx = (b - LN0_BLKS - HIST_BLKS - WP0_BLKS - WP12_BLKS) * 256 + t;
        wprep_body(idx, 2, Wq2, Wk2, Wv2, Ws2, Wp2);
    }
}

// ---------------------------------------------------------------------------
// Single-block exclusive scan over the 38416-entry flattened histogram.
__global__ __launch_bounds__(1024) void scan_all_kernel(
        const int* __restrict__ ghist, int* __restrict__ goff,
        int* __restrict__ bbase, int* __restrict__ row_ptr) {
    __shared__ int wsum[16];
    int t = threadIdx.x;
    int lane = t & 63;
    int w = t >> 6;
    int carry = 0;
    for (int base = 0; base < FLAT; base += 1024) {
        int f = base + t;
        int v = (f < FLAT) ? ghist[f] : 0;
        int incl = v;
        #pragma unroll
        for (int off = 1; off < 64; off <<= 1) {
            int tt = __shfl_up(incl, off);
            if (lane >= off) incl += tt;
        }
        if (lane == 63) wsum[w] = incl;
        __syncthreads();
        int woff = 0, total = 0;
        #pragma unroll
        for (int k = 0; k < 16; k++) {
            int s = wsum[k];
            total += s;
            if (k < w) woff += s;
        }
        int excl = carry + woff + incl - v;
        if (f < FLAT) {
            goff[f] = excl;
            if (f % SB == 0) bbase[f / SB] = excl;
        }
        carry += total;
        __syncthreads();
    }
    if (t == 0) { bbase[NBK] = N_EDGES; row_ptr[N_NODES] = N_EDGES; }
}

// ---------------------------------------------------------------------------
// Deterministic scatter into compact bucket-sorted edge array.
__global__ __launch_bounds__(256) void scatter_kernel(
        const int* __restrict__ src, const int* __restrict__ dst,
        const int* __restrict__ goff, int2* __restrict__ ebkt) {
    __shared__ int hist[NBK];
    int t = threadIdx.x, i = blockIdx.x;
    for (int k = t; k < NBK; k += 256) hist[k] = 0;
    __syncthreads();
    int e0 = i * EPB;
    #pragma unroll
    for (int r = 0; r < EPB / 256; r++) {
        int e = e0 + r * 256 + t;
        if (e < N_EDGES) {
            int s = src[e], d = dst[e];
            int k = d >> 8;
            int rank = atomicAdd(&hist[k], 1);
            ebkt[goff[k * SB + i] + rank] = make_int2(s, d);
        }
    }
}

__global__ __launch_bounds__(256) void bucket_build_kernel(
        const int2* __restrict__ ebkt, const int* __restrict__ bbase,
        int* __restrict__ row_ptr, int* __restrict__ colb) {
    __shared__ int ldeg[256];
    __shared__ int lcur[256];
    __shared__ int wsum[4];
    int b = blockIdx.x;
    int t = threadIdx.x;
    int cbase = bbase[b];
    int cnt = bbase[b + 1] - cbase;

    ldeg[t] = 0;
    __syncthreads();
    for (int i = t; i < cnt; i += 256) {
        int2 e = ebkt[cbase + i];
        atomicAdd(&ldeg[e.y & 255], 1);
    }
    __syncthreads();

    int lane = t & 63;
    int w = t >> 6;
    int v = ldeg[t];
    int incl = v;
    #pragma unroll
    for (int off = 1; off < 64; off <<= 1) {
        int tt = __shfl_up(incl, off);
        if (lane >= off) incl += tt;
    }
    if (lane == 63) wsum[w] = incl;
    __syncthreads();
    int woff = 0;
    #pragma unroll
    for (int k = 0; k < 4; k++) if (k < w) woff += wsum[k];
    int excl = woff + incl - v;

    int node = b * 256 + t;
    if (node < N_NODES) row_ptr[node] = cbase + excl;
    lcur[t] = excl;
    __syncthreads();

    for (int i = t; i < cnt; i += 256) {
        int2 e = ebkt[cbase + i];
        int r = atomicAdd(&lcur[e.y & 255], 1);
        colb[cbase + r] = e.x;
    }
}

// ---------------------------------------------------------------------------
// Kernel: Q/K/V/Skip projections via MFMA. Block = 16 nodes; wave w owns the
// 16-col slice w of each of Q,K,V,S. fp32 accum; biases in fp32.
// K,V packed bf16: KV[n*64+c] = (bf16(V)<<16)|bf16(K).
template <int D>
__global__ __launch_bounds__(256) void qkvs_mfma_kernel(
        const float* __restrict__ h,
        const unsigned short* __restrict__ Wp,
        const float* __restrict__ bq, const float* __restrict__ bk,
        const float* __restrict__ bv,
        float* __restrict__ Q, unsigned int* __restrict__ KV,
        float* __restrict__ S) {
    constexpr int KS = D / 32;
    int t = threadIdx.x;
    int lane = t & 63;
    int w = t >> 6;
    int n0 = blockIdx.x * 16;
    int n16 = lane & 15;
    int quad = lane >> 4;
    int col = w * 16 + n16;

    short8 afrag[KS];
    #pragma unroll
    for (int s = 0; s < KS; s++) {
        const float* hp = &h[(n0 + n16) * D + s * 32 + quad * 8];
        float4 a0 = *(const float4*)hp;
        float4 a1 = *(const float4*)(hp + 4);
        short8 af;
        af[0] = (short)f32_to_bf16_rne(a0.x);
        af[1] = (short)f32_to_bf16_rne(a0.y);
        af[2] = (short)f32_to_bf16_rne(a0.z);
        af[3] = (short)f32_to_bf16_rne(a0.w);
        af[4] = (short)f32_to_bf16_rne(a1.x);
        af[5] = (short)f32_to_bf16_rne(a1.y);
        af[6] = (short)f32_to_bf16_rne(a1.z);
        af[7] = (short)f32_to_bf16_rne(a1.w);
        afrag[s] = af;
    }

    float4v accs[4];
    #pragma unroll
    for (int which = 0; which < 4; which++) {
        float4v acc = {0.0f, 0.0f, 0.0f, 0.0f};
        int tile = which * 4 + w;
        #pragma unroll
        for (int s = 0; s < KS; s++) {
            short8 bfrag = *(const short8*)&Wp[((tile * KS + s) * 64 + lane) * 8];
            acc = __builtin_amdgcn_mfma_f32_16x16x32_bf16(afrag[s], bfrag, acc, 0, 0, 0);
        }
        accs[which] = acc;
    }

    float bqc = bq[col], bkc = bk[col], bvc = bv[col];

    #pragma unroll
    for (int r = 0; r < 4; r++) {
        int node = n0 + quad * 4 + r;
        Q[node * 64 + col] = accs[0][r] + bqc;
        unsigned int kw = f32_to_bf16_rne(accs[1][r] + bkc);
        unsigned int vw = f32_to_bf16_rne(accs[2][r] + bvc);
        KV[node * 64 + col] = (vw << 16) | kw;
        S[node * 64 + col] = accs[3][r];
    }
}

// ---------------------------------------------------------------------------
// Kernel: per-node attention aggregation + skip + LayerNorm (+res/relu).
// One wave per node, 4 groups of 16 lanes; 16-edge batched gathers.
// HEAD=true (layer 2): fuse the two MLP heads via LDS and skip the h_out
// store (layer-2 h has no other consumer).
template <int HEADS, bool RES, bool RELU, bool HEAD>
__global__ __launch_bounds__(256) void agg_kernel(
                           const float* __restrict__ Q, const unsigned int* __restrict__ KV,
                           const float* __restrict__ S,
                           const int* __restrict__ row_ptr, const int* __restrict__ colb,
                           const float* __restrict__ g, const float* __restrict__ b,
                           const float* __restrict__ h_in, float* __restrict__ h_out,
                           const float* __restrict__ Wr1, const float* __restrict__ br1,
                           const float* __restrict__ Wr2, const float* __restrict__ br2,
                           const float* __restrict__ Wt1, const float* __restrict__ bt1,
                           const float* __restrict__ Wt2, const float* __restrict__ bt2,
                           float* __restrict__ out) {
    constexpr int C = HID / HEADS;
    int lane = threadIdx.x & 63;
    int m = lane & 15;
    int grp = lane >> 4;
    int n = blockIdx.x * 4 + (threadIdx.x >> 6);

    const float scale = rsqrtf((float)C);
    float4 q4 = *(const float4*)&Q[n * 64 + 4 * m];
    q4.x *= scale; q4.y *= scale; q4.z *= scale; q4.w *= scale;

    int beg = row_ptr[n], end = row_ptr[n + 1];

    float ssum = 0.0f;
    float acc0 = 0.0f, acc1 = 0.0f, acc2 = 0.0f, acc3 = 0.0f;

    for (int base = beg; base < end; base += 64) {
        int limit = min(end - base, 64);
        int src_l = (base + lane < end) ? colb[base + lane] : 0;
        for (int sub = 0; sub < limit; sub += 16) {
            int e0 = sub + grp, e1 = sub + 4 + grp, e2 = sub + 8 + grp, e3 = sub + 12 + grp;
            int s0 = __shfl(src_l, e0);
            int s1 = __shfl(src_l, e1);
            int s2 = __shfl(src_l, e2);
            int s3 = __shfl(src_l, e3);
            bool v0ok = e0 < limit, v1ok = e1 < limit, v2ok = e2 < limit, v3ok = e3 < limit;
            uint4 kv0 = make_uint4(0, 0, 0, 0), kv1 = kv0, kv2 = kv0, kv3 = kv0;
            if (v0ok) kv0 = *(const uint4*)&KV[(size_t)s0 * 64 + 4 * m];
            if (v1ok) kv1 = *(const uint4*)&KV[(size_t)s1 * 64 + 4 * m];
            if (v2ok) kv2 = *(const uint4*)&KV[(size_t)s2 * 64 + 4 * m];
            if (v3ok) kv3 = *(const uint4*)&KV[(size_t)s3 * 64 + 4 * m];

            float t0 = fmaf(q4.x, __uint_as_float(kv0.x << 16),
                       fmaf(q4.y, __uint_as_float(kv0.y << 16),
                       fmaf(q4.z, __uint_as_float(kv0.z << 16),
                            q4.w * __uint_as_float(kv0.w << 16))));
            float t1 = fmaf(q4.x, __uint_as_float(kv1.x << 16),
                       fmaf(q4.y, __uint_as_float(kv1.y << 16),
                       fmaf(q4.z, __uint_as_float(kv1.z << 16),
                            q4.w * __uint_as_float(kv1.w << 16))));
            float t2 = fmaf(q4.x, __uint_as_float(kv2.x << 16),
                       fmaf(q4.y, __uint_as_float(kv2.y << 16),
                       fmaf(q4.z, __uint_as_float(kv2.z << 16),
                            q4.w * __uint_as_float(kv2.w << 16))));
            float t3 = fmaf(q4.x, __uint_as_float(kv3.x << 16),
                       fmaf(q4.y, __uint_as_float(kv3.y << 16),
                       fmaf(q4.z, __uint_as_float(kv3.z << 16),
                            q4.w * __uint_as_float(kv3.w << 16))));
            #pragma unroll
            for (int off = 1; off < C / 4; off <<= 1) {
                t0 += __shfl_xor(t0, off);
                t1 += __shfl_xor(t1, off);
                t2 += __shfl_xor(t2, off);
                t3 += __shfl_xor(t3, off);
            }
            float p0 = v0ok ? __expf(t0) : 0.0f;
            float p1 = v1ok ? __expf(t1) : 0.0f;
            float p2 = v2ok ? __expf(t2) : 0.0f;
            float p3 = v3ok ? __expf(t3) : 0.0f;
            ssum += (p0 + p1) + (p2 + p3);
            acc0 = fmaf(p0, __uint_as_float(kv0.x & 0xffff0000u),
                   fmaf(p1, __uint_as_float(kv1.x & 0xffff0000u),
                   fmaf(p2, __uint_as_float(kv2.x & 0xffff0000u),
                   fmaf(p3, __uint_as_float(kv3.x & 0xffff0000u), acc0))));
            acc1 = fmaf(p0, __uint_as_float(kv0.y & 0xffff0000u),
                   fmaf(p1, __uint_as_float(kv1.y & 0xffff0000u),
                   fmaf(p2, __uint_as_float(kv2.y & 0xffff0000u),
                   fmaf(p3, __uint_as_float(kv3.y & 0xffff0000u), acc1))));
            acc2 = fmaf(p0, __uint_as_float(kv0.z & 0xffff0000u),
                   fmaf(p1, __uint_as_float(kv1.z & 0xffff0000u),
                   fmaf(p2, __uint_as_float(kv2.z & 0xffff0000u),
                   fmaf(p3, __uint_as_float(kv3.z & 0xffff0000u), acc2))));
            acc3 = fmaf(p0, __uint_as_float(kv0.w & 0xffff0000u),
                   fmaf(p1, __uint_as_float(kv1.w & 0xffff0000u),
                   fmaf(p2, __uint_as_float(kv2.w & 0xffff0000u),
                   fmaf(p3, __uint_as_float(kv3.w & 0xffff0000u), acc3))));
        }
    }

    #pragma unroll
    for (int off = 16; off < 64; off <<= 1) {
        ssum += __shfl_xor(ssum, off);
        acc0 += __shfl_xor(acc0, off);
        acc1 += __shfl_xor(acc1, off);
        acc2 += __shfl_xor(acc2, off);
        acc3 += __shfl_xor(acc3, off);
    }

    float inv = 1.0f / (ssum + 1e-16f);
    float4 sv = *(const float4*)&S[n * 64 + 4 * m];
    float o0 = fmaf(acc0, inv, sv.x);
    float o1 = fmaf(acc1, inv, sv.y);
    float o2 = fmaf(acc2, inv, sv.z);
    float o3 = fmaf(acc3, inv, sv.w);

    float s = (o0 + o1) + (o2 + o3);
    #pragma unroll
    for (int off = 1; off < 16; off <<= 1) s += __shfl_xor(s, off);
    float mu = s * (1.0f / 64.0f);
    float d0 = o0 - mu, d1 = o1 - mu, d2 = o2 - mu, d3 = o3 - mu;
    float vs = (d0 * d0 + d1 * d1) + (d2 * d2 + d3 * d3);
    #pragma unroll
    for (int off = 1; off < 16; off <<= 1) vs += __shfl_xor(vs, off);
    float rstd = rsqrtf(vs * (1.0f / 64.0f) + 1e-5f);

    float4 gv = *(const float4*)&g[4 * m];
    float4 bv = *(const float4*)&b[4 * m];
    float y0 = d0 * rstd * gv.x + bv.x;
    float y1 = d1 * rstd * gv.y + bv.y;
    float y2 = d2 * rstd * gv.z + bv.z;
    float y3 = d3 * rstd * gv.w + bv.w;
    if (RES) {
        float4 rv = *(const float4*)&h_in[n * 64 + 4 * m];
        y0 = fmaf(0.1f, rv.x, y0);
        y1 = fmaf(0.1f, rv.y, y1);
        y2 = fmaf(0.1f, rv.z, y2);
        y3 = fmaf(0.1f, rv.w, y3);
    }
    if (RELU) {
        y0 = fmaxf(y0, 0.0f); y1 = fmaxf(y1, 0.0f);
        y2 = fmaxf(y2, 0.0f); y3 = fmaxf(y3, 0.0f);
    }

    if (!HEAD) {
        if (grp == 0) {
            float4 yv = make_float4(y0, y1, y2, y3);
            *(float4*)&h_out[n * 64 + 4 * m] = yv;
        }
    } else {
        __shared__ float sh[4][HID];
        int wave = threadIdx.x >> 6;
        if (grp == 0) {
            float4 yv = make_float4(y0, y1, y2, y3);
            *(float4*)&sh[wave][4 * m] = yv;
        }
        __syncthreads();
        int half = lane >> 5;
        int j = lane & 31;
        const float* W1 = half ? Wt1 : Wr1;
        const float* b1 = half ? bt1 : br1;
        const float* W2 = half ? Wt2 : Wr2;
        const float* b2v = half ? bt2 : br2;
        float a = b1[j];
        #pragma unroll 8
        for (int i = 0; i < 64; i++) a = fmaf(sh[wave][i], W1[i * 32 + j], a);
        a = fmaxf(a, 0.0f);
        float r = a * W2[j];
        #pragma unroll
        for (int off = 1; off < 32; off <<= 1) r += __shfl_xor(r, off);
        if (j == 0) out[n * 2 + half] = r + b2v[0];
    }
}

// ---------------------------------------------------------------------------
extern "C" void kernel_launch(void* const* d_in, const int* in_sizes, int n_in,
                              void* d_out, int out_size, void* d_ws, size_t ws_size,
                              hipStream_t stream) {
    const float* x    = (const float*)d_in[0];
    const int*   ei   = (const int*)d_in[1];
    const int*   src  = ei;
    const int*   dst  = ei + N_EDGES;
    const float* ln0g = (const float*)d_in[2];
    const float* ln0b = (const float*)d_in[3];

    const float* P[27];
    for (int i = 0; i < 27; i++) P[i] = (const float*)d_in[4 + i];
    const float* Wr1 = (const float*)d_in[31];
    const float* br1 = (const float*)d_in[32];
    const float* Wr2 = (const float*)d_in[33];
    const float* br2 = (const float*)d_in[34];
    const float* Wt1 = (const float*)d_in[35];
    const float* bt1 = (const float*)d_in[36];
    const float* Wt2 = (const float*)d_in[37];
    const float* bt2 = (const float*)d_in[38];

    float* out = (float*)d_out;

    // workspace layout
    float* hbuf0 = (float*)d_ws;                 // N*64
    float* hbuf1 = hbuf0 + N_NODES * 64;         // N*64
    float* Qb    = hbuf1 + N_NODES * 64;         // N*64
    float* Sb    = Qb + N_NODES * 64;            // N*64
    unsigned int* KVb = (unsigned int*)(Sb + N_NODES * 64);   // N*64 uint
    int* row_ptr = (int*)(KVb + N_NODES * 64);   // N+1
    int* colb    = row_ptr + (N_NODES + 1);      // E
    int* ghist   = colb + N_EDGES;               // FLAT
    int* goff    = ghist + FLAT;                 // FLAT
    int* bbase   = goff + FLAT;                  // NBK+1
    unsigned short* Wp0 = (unsigned short*)(bbase + NBK + 1); // 16*1*512
    unsigned short* Wp1 = Wp0 + 16 * 1 * 512;                 // 16*2*512
    unsigned short* Wp2 = Wp1 + 16 * 2 * 512;                 // 16*2*512
    // ebkt aliases Qb (dead until qkvs0 runs): E int2 = 6.4 MB < 12.8 MB
    int2* ebkt = (int2*)Qb;

    // ---- fused prep (ln0 + bucket hist + weight packs) ----
    prep_kernel<<<PREP_BLKS, 256, 0, stream>>>(x, ln0g, ln0b, hbuf0,
        dst, ghist,
        P[0],  P[2],  P[4],  P[6],  Wp0,
        P[9],  P[11], P[13], P[15], Wp1,
        P[18], P[20], P[22], P[24], Wp2);
    // ---- CSR build ----
    scan_all_kernel<<<1, 1024, 0, stream>>>(ghist, goff, bbase, row_ptr);
    scatter_kernel<<<SB, 256, 0, stream>>>(src, dst, goff, ebkt);
    bucket_build_kernel<<<NBK, 256, 0, stream>>>(ebkt, bbase, row_ptr, colb);

    // ---- layer 0: 32 -> 64, heads=4, no residual, relu ----
    qkvs_mfma_kernel<32><<<3125, 256, 0, stream>>>(hbuf0, Wp0,
        P[1], P[3], P[5], Qb, KVb, Sb);
    agg_kernel<4, false, true, false><<<12500, 256, 0, stream>>>(Qb, KVb, Sb,
        row_ptr, colb, P[7], P[8], nullptr, hbuf1,
        Wr1, br1, Wr2, br2, Wt1, bt1, Wt2, bt2, out);

    // ---- layer 1: 64 -> 64, heads=4, residual, relu ----
    qkvs_mfma_kernel<64><<<3125, 256, 0, stream>>>(hbuf1, Wp1,
        P[10], P[12], P[14], Qb, KVb, Sb);
    agg_kernel<4, true, true, false><<<12500, 256, 0, stream>>>(Qb, KVb, Sb,
        row_ptr, colb, P[16], P[17], hbuf1, hbuf0,
        Wr1, br1, Wr2, br2, Wt1, bt1, Wt2, bt2, out);

    // ---- layer 2: 64 -> 64, heads=1, residual, no relu + fused MLP heads ----
    qkvs_mfma_kernel<64><<<3125, 256, 0, stream>>>(hbuf0, Wp2,
        P[19], P[21], P[23], Qb, KVb, Sb);
    agg_kernel<1, true, false, true><<<12500, 256, 0, stream>>>(Qb, KVb, Sb,
        row_ptr, colb, P[25], P[26], hbuf0, hbuf1,
        Wr1, br1, Wr2, br2, Wt1, bt1, Wt2, bt2, out);
}

// Round 16
// 334.912 us; speedup vs baseline: 1.0842x; 1.0842x over previous
//
#include <hip/hip_runtime.h>
#include <hip/hip_bf16.h>
#include <math.h>

#define N_NODES 50000
#define N_EDGES 800000
#define HID 64
#define NBK 196          // buckets of 256 nodes
#define EPB 1024         // edges per hist/scatter block
#define SB  ((N_EDGES + EPB - 1) / EPB)   // 782
#define FLAT (NBK * SB)  // 153272 flattened (bucket-major) histogram entries
#define SCAN_B ((FLAT + 255) / 256)  // 599

// fused prep grid partition
#define LN0_BLKS   6250
#define HIST_BLKS  SB
#define WP0_BLKS   32    // 16*1*512 / 256
#define WP12_BLKS  64    // 16*2*512 / 256
#define PREP_BLKS  (LN0_BLKS + HIST_BLKS + WP0_BLKS + 2 * WP12_BLKS)

typedef __attribute__((ext_vector_type(8))) short short8;
typedef __attribute__((ext_vector_type(4))) float float4v;

__device__ __forceinline__ unsigned short f32_to_bf16_rne(float f) {
    unsigned int u = __float_as_uint(f);
    unsigned int r = u + 0x7fffu + ((u >> 16) & 1u);
    return (unsigned short)(r >> 16);
}

// ---------------------------------------------------------------------------
// Device helpers for the fused prep kernel.
__device__ __forceinline__ void ln0_body(int b, int t,
        const float* __restrict__ x, const float* __restrict__ g,
        const float* __restrict__ bb, float* __restrict__ h0) {
    int lane = t & 63;
    int n = b * 8 + (t >> 6) * 2 + (lane >> 5);
    int c = lane & 31;
    float v = x[n * 32 + c];
    float s = v;
    #pragma unroll
    for (int off = 1; off < 32; off <<= 1) s += __shfl_xor(s, off);
    float mu = s * (1.0f / 32.0f);
    float d = v - mu;
    float vs = d * d;
    #pragma unroll
    for (int off = 1; off < 32; off <<= 1) vs += __shfl_xor(vs, off);
    float var = vs * (1.0f / 32.0f);
    h0[n * 32 + c] = d * rsqrtf(var + 1e-5f) * g[c] + bb[c];
}

__device__ __forceinline__ void wprep_body(int idx, int KS,
        const float* __restrict__ Wq, const float* __restrict__ Wk,
        const float* __restrict__ Wv, const float* __restrict__ Ws,
        unsigned short* __restrict__ Wp) {
    int j = idx & 7;
    int lane = (idx >> 3) & 63;
    int ts = idx >> 9;            // tile*KS + s
    int s = ts % KS;
    int tile = ts / KS;
    int which = tile >> 2;
    int slice = tile & 3;
    int k = s * 32 + ((lane >> 4) * 8) + j;
    int col = slice * 16 + (lane & 15);
    const float* W = (which == 0) ? Wq : (which == 1) ? Wk : (which == 2) ? Wv : Ws;
    Wp[idx] = f32_to_bf16_rne(W[k * 64 + col]);
}

// ---------------------------------------------------------------------------
// Fused prep: ln0 + per-block bucket histogram + 3x weight pack.
__global__ __launch_bounds__(256) void prep_kernel(
        const float* __restrict__ x, const float* __restrict__ ln0g,
        const float* __restrict__ ln0b, float* __restrict__ h0,
        const int* __restrict__ dst, int* __restrict__ ghist,
        const float* __restrict__ Wq0, const float* __restrict__ Wk0,
        const float* __restrict__ Wv0, const float* __restrict__ Ws0,
        unsigned short* __restrict__ Wp0,
        const float* __restrict__ Wq1, const float* __restrict__ Wk1,
        const float* __restrict__ Wv1, const float* __restrict__ Ws1,
        unsigned short* __restrict__ Wp1,
        const float* __restrict__ Wq2, const float* __restrict__ Wk2,
        const float* __restrict__ Wv2, const float* __restrict__ Ws2,
        unsigned short* __restrict__ Wp2) {
    __shared__ int hist[NBK];
    int b = blockIdx.x;
    int t = threadIdx.x;
    if (b < LN0_BLKS) {
        ln0_body(b, t, x, ln0g, ln0b, h0);
    } else if (b < LN0_BLKS + HIST_BLKS) {
        int i = b - LN0_BLKS;
        for (int k = t; k < NBK; k += 256) hist[k] = 0;
        __syncthreads();
        int e0 = i * EPB;
        #pragma unroll
        for (int r = 0; r < EPB / 256; r++) {
            int e = e0 + r * 256 + t;
            if (e < N_EDGES) atomicAdd(&hist[dst[e] >> 8], 1);
        }
        __syncthreads();
        for (int k = t; k < NBK; k += 256) ghist[k * SB + i] = hist[k];
    } else if (b < LN0_BLKS + HIST_BLKS + WP0_BLKS) {
        int idx = (b - LN0_BLKS - HIST_BLKS) * 256 + t;
        wprep_body(idx, 1, Wq0, Wk0, Wv0, Ws0, Wp0);
    } else if (b < LN0_BLKS + HIST_BLKS + WP0_BLKS + WP12_BLKS) {
        int idx = (b - LN0_BLKS - HIST_BLKS - WP0_BLKS) * 256 + t;
        wprep_body(idx, 2, Wq1, Wk1, Wv1, Ws1, Wp1);
    } else {
        int idx = (b - LN0_BLKS - HIST_BLKS - WP0_BLKS - WP12_BLKS) * 256 + t;
        wprep_body(idx, 2, Wq2, Wk2, Wv2, Ws2, Wp2);
    }
}

// ---------------------------------------------------------------------------
// CSR build scans (deterministic, no global atomics). Separate kernels:
// stream-ordered dispatch boundaries are CHEAPER than cooperative grid.sync
// (R12: coop fusion cost 340 us) AND cheaper than a single-block serial scan
// (R15: scan_all regressed ~20 us vs these three).
__global__ void scan1_kernel(const int* __restrict__ ghist, int* __restrict__ csum) {
    int f = blockIdx.x * 256 + threadIdx.x;
    int v = (f < FLAT) ? ghist[f] : 0;
    #pragma unroll
    for (int off = 1; off < 64; off <<= 1) v += __shfl_xor(v, off);
    __shared__ int ws[4];
    if ((threadIdx.x & 63) == 0) ws[threadIdx.x >> 6] = v;
    __syncthreads();
    if (threadIdx.x == 0) csum[blockIdx.x] = ws[0] + ws[1] + ws[2] + ws[3];
}

__global__ void scan2_kernel(const int* __restrict__ csum, int* __restrict__ coff,
                             int* __restrict__ bbase, int* __restrict__ row_ptr) {
    int lane = threadIdx.x;
    int carry = 0;
    for (int base = 0; base < SCAN_B; base += 64) {
        int i = base + lane;
        int v = (i < SCAN_B) ? csum[i] : 0;
        int incl = v;
        #pragma unroll
        for (int off = 1; off < 64; off <<= 1) {
            int tt = __shfl_up(incl, off);
            if (lane >= off) incl += tt;
        }
        if (i < SCAN_B) coff[i] = carry + incl - v;
        carry += __shfl(incl, 63);
    }
    if (lane == 0) { bbase[NBK] = N_EDGES; row_ptr[N_NODES] = N_EDGES; }
}

__global__ void scan3_kernel(const int* __restrict__ ghist, const int* __restrict__ coff,
                             int* __restrict__ goff, int* __restrict__ bbase) {
    int f = blockIdx.x * 256 + threadIdx.x;
    int lane = threadIdx.x & 63;
    int w = threadIdx.x >> 6;
    int v = (f < FLAT) ? ghist[f] : 0;
    int incl = v;
    #pragma unroll
    for (int off = 1; off < 64; off <<= 1) {
        int tt = __shfl_up(incl, off);
        if (lane >= off) incl += tt;
    }
    __shared__ int ws[4];
    if (lane == 63) ws[w] = incl;
    __syncthreads();
    int woff = 0;
    #pragma unroll
    for (int k = 0; k < 4; k++) if (k < w) woff += ws[k];
    int excl = coff[blockIdx.x] + woff + incl - v;
    if (f < FLAT) {
        goff[f] = excl;
        if (f % SB == 0) bbase[f / SB] = excl;
    }
}

__global__ __launch_bounds__(256) void scatter_kernel(
        const int* __restrict__ src, const int* __restrict__ dst,
        const int* __restrict__ goff, int2* __restrict__ ebkt) {
    __shared__ int hist[NBK];
    int t = threadIdx.x, i = blockIdx.x;
    for (int k = t; k < NBK; k += 256) hist[k] = 0;
    __syncthreads();
    int e0 = i * EPB;
    #pragma unroll
    for (int r = 0; r < EPB / 256; r++) {
        int e = e0 + r * 256 + t;
        if (e < N_EDGES) {
            int s = src[e], d = dst[e];
            int k = d >> 8;
            int rank = atomicAdd(&hist[k], 1);
            ebkt[goff[k * SB + i] + rank] = make_int2(s, d);
        }
    }
}

__global__ __launch_bounds__(256) void bucket_build_kernel(
        const int2* __restrict__ ebkt, const int* __restrict__ bbase,
        int* __restrict__ row_ptr, int* __restrict__ colb) {
    __shared__ int ldeg[256];
    __shared__ int lcur[256];
    __shared__ int wsum[4];
    int b = blockIdx.x;
    int t = threadIdx.x;
    int cbase = bbase[b];
    int cnt = bbase[b + 1] - cbase;

    ldeg[t] = 0;
    __syncthreads();
    for (int i = t; i < cnt; i += 256) {
        int2 e = ebkt[cbase + i];
        atomicAdd(&ldeg[e.y & 255], 1);
    }
    __syncthreads();

    int lane = t & 63;
    int w = t >> 6;
    int v = ldeg[t];
    int incl = v;
    #pragma unroll
    for (int off = 1; off < 64; off <<= 1) {
        int tt = __shfl_up(incl, off);
        if (lane >= off) incl += tt;
    }
    if (lane == 63) wsum[w] = incl;
    __syncthreads();
    int woff = 0;
    #pragma unroll
    for (int k = 0; k < 4; k++) if (k < w) woff += wsum[k];
    int excl = woff + incl - v;

    int node = b * 256 + t;
    if (node < N_NODES) row_ptr[node] = cbase + excl;
    lcur[t] = excl;
    __syncthreads();

    for (int i = t; i < cnt; i += 256) {
        int2 e = ebkt[cbase + i];
        int r = atomicAdd(&lcur[e.y & 255], 1);
        colb[cbase + r] = e.x;
    }
}

// ---------------------------------------------------------------------------
// Kernel: Q/K/V/Skip projections via MFMA. Block = 16 nodes; wave w owns the
// 16-col slice w of each of Q,K,V,S. fp32 accum; biases in fp32.
// K,V packed bf16: KV[n*64+c] = (bf16(V)<<16)|bf16(K).
template <int D>
__global__ __launch_bounds__(256) void qkvs_mfma_kernel(
        const float* __restrict__ h,
        const unsigned short* __restrict__ Wp,
        const float* __restrict__ bq, const float* __restrict__ bk,
        const float* __restrict__ bv,
        float* __restrict__ Q, unsigned int* __restrict__ KV,
        float* __restrict__ S) {
    constexpr int KS = D / 32;
    int t = threadIdx.x;
    int lane = t & 63;
    int w = t >> 6;
    int n0 = blockIdx.x * 16;
    int n16 = lane & 15;
    int quad = lane >> 4;
    int col = w * 16 + n16;

    short8 afrag[KS];
    #pragma unroll
    for (int s = 0; s < KS; s++) {
        const float* hp = &h[(n0 + n16) * D + s * 32 + quad * 8];
        float4 a0 = *(const float4*)hp;
        float4 a1 = *(const float4*)(hp + 4);
        short8 af;
        af[0] = (short)f32_to_bf16_rne(a0.x);
        af[1] = (short)f32_to_bf16_rne(a0.y);
        af[2] = (short)f32_to_bf16_rne(a0.z);
        af[3] = (short)f32_to_bf16_rne(a0.w);
        af[4] = (short)f32_to_bf16_rne(a1.x);
        af[5] = (short)f32_to_bf16_rne(a1.y);
        af[6] = (short)f32_to_bf16_rne(a1.z);
        af[7] = (short)f32_to_bf16_rne(a1.w);
        afrag[s] = af;
    }

    float4v accs[4];
    #pragma unroll
    for (int which = 0; which < 4; which++) {
        float4v acc = {0.0f, 0.0f, 0.0f, 0.0f};
        int tile = which * 4 + w;
        #pragma unroll
        for (int s = 0; s < KS; s++) {
            short8 bfrag = *(const short8*)&Wp[((tile * KS + s) * 64 + lane) * 8];
            acc = __builtin_amdgcn_mfma_f32_16x16x32_bf16(afrag[s], bfrag, acc, 0, 0, 0);
        }
        accs[which] = acc;
    }

    float bqc = bq[col], bkc = bk[col], bvc = bv[col];

    #pragma unroll
    for (int r = 0; r < 4; r++) {
        int node = n0 + quad * 4 + r;
        Q[node * 64 + col] = accs[0][r] + bqc;
        unsigned int kw = f32_to_bf16_rne(accs[1][r] + bkc);
        unsigned int vw = f32_to_bf16_rne(accs[2][r] + bvc);
        KV[node * 64 + col] = (vw << 16) | kw;
        S[node * 64 + col] = accs[3][r];
    }
}

// ---------------------------------------------------------------------------
// Kernel: per-node attention aggregation + skip + LayerNorm (+res/relu).
// One wave per node, 4 groups of 16 lanes; 16-edge batched gathers.
// HEAD=true (layer 2): fuse the two MLP heads via LDS and skip the h_out
// store (layer-2 h has no other consumer).
template <int HEADS, bool RES, bool RELU, bool HEAD>
__global__ __launch_bounds__(256) void agg_kernel(
                           const float* __restrict__ Q, const unsigned int* __restrict__ KV,
                           const float* __restrict__ S,
                           const int* __restrict__ row_ptr, const int* __restrict__ colb,
                           const float* __restrict__ g, const float* __restrict__ b,
                           const float* __restrict__ h_in, float* __restrict__ h_out,
                           const float* __restrict__ Wr1, const float* __restrict__ br1,
                           const float* __restrict__ Wr2, const float* __restrict__ br2,
                           const float* __restrict__ Wt1, const float* __restrict__ bt1,
                           const float* __restrict__ Wt2, const float* __restrict__ bt2,
                           float* __restrict__ out) {
    constexpr int C = HID / HEADS;
    int lane = threadIdx.x & 63;
    int m = lane & 15;
    int grp = lane >> 4;
    int n = blockIdx.x * 4 + (threadIdx.x >> 6);

    const float scale = rsqrtf((float)C);
    float4 q4 = *(const float4*)&Q[n * 64 + 4 * m];
    q4.x *= scale; q4.y *= scale; q4.z *= scale; q4.w *= scale;

    int beg = row_ptr[n], end = row_ptr[n + 1];

    float ssum = 0.0f;
    float acc0 = 0.0f, acc1 = 0.0f, acc2 = 0.0f, acc3 = 0.0f;

    for (int base = beg; base < end; base += 64) {
        int limit = min(end - base, 64);
        int src_l = (base + lane < end) ? colb[base + lane] : 0;
        for (int sub = 0; sub < limit; sub += 16) {
            int e0 = sub + grp, e1 = sub + 4 + grp, e2 = sub + 8 + grp, e3 = sub + 12 + grp;
            int s0 = __shfl(src_l, e0);
            int s1 = __shfl(src_l, e1);
            int s2 = __shfl(src_l, e2);
            int s3 = __shfl(src_l, e3);
            bool v0ok = e0 < limit, v1ok = e1 < limit, v2ok = e2 < limit, v3ok = e3 < limit;
            uint4 kv0 = make_uint4(0, 0, 0, 0), kv1 = kv0, kv2 = kv0, kv3 = kv0;
            if (v0ok) kv0 = *(const uint4*)&KV[(size_t)s0 * 64 + 4 * m];
            if (v1ok) kv1 = *(const uint4*)&KV[(size_t)s1 * 64 + 4 * m];
            if (v2ok) kv2 = *(const uint4*)&KV[(size_t)s2 * 64 + 4 * m];
            if (v3ok) kv3 = *(const uint4*)&KV[(size_t)s3 * 64 + 4 * m];

            float t0 = fmaf(q4.x, __uint_as_float(kv0.x << 16),
                       fmaf(q4.y, __uint_as_float(kv0.y << 16),
                       fmaf(q4.z, __uint_as_float(kv0.z << 16),
                            q4.w * __uint_as_float(kv0.w << 16))));
            float t1 = fmaf(q4.x, __uint_as_float(kv1.x << 16),
                       fmaf(q4.y, __uint_as_float(kv1.y << 16),
                       fmaf(q4.z, __uint_as_float(kv1.z << 16),
                            q4.w * __uint_as_float(kv1.w << 16))));
            float t2 = fmaf(q4.x, __uint_as_float(kv2.x << 16),
                       fmaf(q4.y, __uint_as_float(kv2.y << 16),
                       fmaf(q4.z, __uint_as_float(kv2.z << 16),
                            q4.w * __uint_as_float(kv2.w << 16))));
            float t3 = fmaf(q4.x, __uint_as_float(kv3.x << 16),
                       fmaf(q4.y, __uint_as_float(kv3.y << 16),
                       fmaf(q4.z, __uint_as_float(kv3.z << 16),
                            q4.w * __uint_as_float(kv3.w << 16))));
            #pragma unroll
            for (int off = 1; off < C / 4; off <<= 1) {
                t0 += __shfl_xor(t0, off);
                t1 += __shfl_xor(t1, off);
                t2 += __shfl_xor(t2, off);
                t3 += __shfl_xor(t3, off);
            }
            float p0 = v0ok ? __expf(t0) : 0.0f;
            float p1 = v1ok ? __expf(t1) : 0.0f;
            float p2 = v2ok ? __expf(t2) : 0.0f;
            float p3 = v3ok ? __expf(t3) : 0.0f;
            ssum += (p0 + p1) + (p2 + p3);
            acc0 = fmaf(p0, __uint_as_float(kv0.x & 0xffff0000u),
                   fmaf(p1, __uint_as_float(kv1.x & 0xffff0000u),
                   fmaf(p2, __uint_as_float(kv2.x & 0xffff0000u),
                   fmaf(p3, __uint_as_float(kv3.x & 0xffff0000u), acc0))));
            acc1 = fmaf(p0, __uint_as_float(kv0.y & 0xffff0000u),
                   fmaf(p1, __uint_as_float(kv1.y & 0xffff0000u),
                   fmaf(p2, __uint_as_float(kv2.y & 0xffff0000u),
                   fmaf(p3, __uint_as_float(kv3.y & 0xffff0000u), acc1))));
            acc2 = fmaf(p0, __uint_as_float(kv0.z & 0xffff0000u),
                   fmaf(p1, __uint_as_float(kv1.z & 0xffff0000u),
                   fmaf(p2, __uint_as_float(kv2.z & 0xffff0000u),
                   fmaf(p3, __uint_as_float(kv3.z & 0xffff0000u), acc2))));
            acc3 = fmaf(p0, __uint_as_float(kv0.w & 0xffff0000u),
                   fmaf(p1, __uint_as_float(kv1.w & 0xffff0000u),
                   fmaf(p2, __uint_as_float(kv2.w & 0xffff0000u),
                   fmaf(p3, __uint_as_float(kv3.w & 0xffff0000u), acc3))));
        }
    }

    #pragma unroll
    for (int off = 16; off < 64; off <<= 1) {
        ssum += __shfl_xor(ssum, off);
        acc0 += __shfl_xor(acc0, off);
        acc1 += __shfl_xor(acc1, off);
        acc2 += __shfl_xor(acc2, off);
        acc3 += __shfl_xor(acc3, off);
    }

    float inv = 1.0f / (ssum + 1e-16f);
    float4 sv = *(const float4*)&S[n * 64 + 4 * m];
    float o0 = fmaf(acc0, inv, sv.x);
    float o1 = fmaf(acc1, inv, sv.y);
    float o2 = fmaf(acc2, inv, sv.z);
    float o3 = fmaf(acc3, inv, sv.w);

    float s = (o0 + o1) + (o2 + o3);
    #pragma unroll
    for (int off = 1; off < 16; off <<= 1) s += __shfl_xor(s, off);
    float mu = s * (1.0f / 64.0f);
    float d0 = o0 - mu, d1 = o1 - mu, d2 = o2 - mu, d3 = o3 - mu;
    float vs = (d0 * d0 + d1 * d1) + (d2 * d2 + d3 * d3);
    #pragma unroll
    for (int off = 1; off < 16; off <<= 1) vs += __shfl_xor(vs, off);
    float rstd = rsqrtf(vs * (1.0f / 64.0f) + 1e-5f);

    float4 gv = *(const float4*)&g[4 * m];
    float4 bv = *(const float4*)&b[4 * m];
    float y0 = d0 * rstd * gv.x + bv.x;
    float y1 = d1 * rstd * gv.y + bv.y;
    float y2 = d2 * rstd * gv.z + bv.z;
    float y3 = d3 * rstd * gv.w + bv.w;
    if (RES) {
        float4 rv = *(const float4*)&h_in[n * 64 + 4 * m];
        y0 = fmaf(0.1f, rv.x, y0);
        y1 = fmaf(0.1f, rv.y, y1);
        y2 = fmaf(0.1f, rv.z, y2);
        y3 = fmaf(0.1f, rv.w, y3);
    }
    if (RELU) {
        y0 = fmaxf(y0, 0.0f); y1 = fmaxf(y1, 0.0f);
        y2 = fmaxf(y2, 0.0f); y3 = fmaxf(y3, 0.0f);
    }

    if (!HEAD) {
        if (grp == 0) {
            float4 yv = make_float4(y0, y1, y2, y3);
            *(float4*)&h_out[n * 64 + 4 * m] = yv;
        }
    } else {
        __shared__ float sh[4][HID];
        int wave = threadIdx.x >> 6;
        if (grp == 0) {
            float4 yv = make_float4(y0, y1, y2, y3);
            *(float4*)&sh[wave][4 * m] = yv;
        }
        __syncthreads();
        int half = lane >> 5;
        int j = lane & 31;
        const float* W1 = half ? Wt1 : Wr1;
        const float* b1 = half ? bt1 : br1;
        const float* W2 = half ? Wt2 : Wr2;
        const float* b2v = half ? bt2 : br2;
        float a = b1[j];
        #pragma unroll 8
        for (int i = 0; i < 64; i++) a = fmaf(sh[wave][i], W1[i * 32 + j], a);
        a = fmaxf(a, 0.0f);
        float r = a * W2[j];
        #pragma unroll
        for (int off = 1; off < 32; off <<= 1) r += __shfl_xor(r, off);
        if (j == 0) out[n * 2 + half] = r + b2v[0];
    }
}

// ---------------------------------------------------------------------------
extern "C" void kernel_launch(void* const* d_in, const int* in_sizes, int n_in,
                              void* d_out, int out_size, void* d_ws, size_t ws_size,
                              hipStream_t stream) {
    const float* x    = (const float*)d_in[0];
    const int*   ei   = (const int*)d_in[1];
    const int*   src  = ei;
    const int*   dst  = ei + N_EDGES;
    const float* ln0g = (const float*)d_in[2];
    const float* ln0b = (const float*)d_in[3];

    const float* P[27];
    for (int i = 0; i < 27; i++) P[i] = (const float*)d_in[4 + i];
    const float* Wr1 = (const float*)d_in[31];
    const float* br1 = (const float*)d_in[32];
    const float* Wr2 = (const float*)d_in[33];
    const float* br2 = (const float*)d_in[34];
    const float* Wt1 = (const float*)d_in[35];
    const float* bt1 = (const float*)d_in[36];
    const float* Wt2 = (const float*)d_in[37];
    const float* bt2 = (const float*)d_in[38];

    float* out = (float*)d_out;

    // workspace layout
    float* hbuf0 = (float*)d_ws;                 // N*64
    float* hbuf1 = hbuf0 + N_NODES * 64;         // N*64
    float* Qb    = hbuf1 + N_NODES * 64;         // N*64
    float* Sb    = Qb + N_NODES * 64;            // N*64
    unsigned int* KVb = (unsigned int*)(Sb + N_NODES * 64);   // N*64 uint
    int* row_ptr = (int*)(KVb + N_NODES * 64);   // N+1
    int* colb    = row_ptr + (N_NODES + 1);      // E
    int* ghist   = colb + N_EDGES;               // FLAT
    int* goff    = ghist + FLAT;                 // FLAT
    int* csum    = goff + FLAT;                  // SCAN_B
    int* coff    = csum + SCAN_B;                // SCAN_B
    int* bbase   = coff + SCAN_B;                // NBK+1
    unsigned short* Wp0 = (unsigned short*)(bbase + NBK + 1); // 16*1*512
    unsigned short* Wp1 = Wp0 + 16 * 1 * 512;                 // 16*2*512
    unsigned short* Wp2 = Wp1 + 16 * 2 * 512;                 // 16*2*512
    // ebkt aliases Qb (dead until qkvs0 runs): E int2 = 6.4 MB < 12.8 MB
    int2* ebkt = (int2*)Qb;

    // ---- fused prep (ln0 + bucket hist + weight packs) ----
    prep_kernel<<<PREP_BLKS, 256, 0, stream>>>(x, ln0g, ln0b, hbuf0,
        dst, ghist,
        P[0],  P[2],  P[4],  P[6],  Wp0,
        P[9],  P[11], P[13], P[15], Wp1,
        P[18], P[20], P[22], P[24], Wp2);
    // ---- CSR build (deterministic counting sort, separate kernels) ----
    scan1_kernel<<<SCAN_B, 256, 0, stream>>>(ghist, csum);
    scan2_kernel<<<1, 64, 0, stream>>>(csum, coff, bbase, row_ptr);
    scan3_kernel<<<SCAN_B, 256, 0, stream>>>(ghist, coff, goff, bbase);
    scatter_kernel<<<SB, 256, 0, stream>>>(src, dst, goff, ebkt);
    bucket_build_kernel<<<NBK, 256, 0, stream>>>(ebkt, bbase, row_ptr, colb);

    // ---- layer 0: 32 -> 64, heads=4, no residual, relu ----
    qkvs_mfma_kernel<32><<<3125, 256, 0, stream>>>(hbuf0, Wp0,
        P[1], P[3], P[5], Qb, KVb, Sb);
    agg_kernel<4, false, true, false><<<12500, 256, 0, stream>>>(Qb, KVb, Sb,
        row_ptr, colb, P[7], P[8], nullptr, hbuf1,
        Wr1, br1, Wr2, br2, Wt1, bt1, Wt2, bt2, out);

    // ---- layer 1: 64 -> 64, heads=4, residual, relu ----
    qkvs_mfma_kernel<64><<<3125, 256, 0, stream>>>(hbuf1, Wp1,
        P[10], P[12], P[14], Qb, KVb, Sb);
    agg_kernel<4, true, true, false><<<12500, 256, 0, stream>>>(Qb, KVb, Sb,
        row_ptr, colb, P[16], P[17], hbuf1, hbuf0,
        Wr1, br1, Wr2, br2, Wt1, bt1, Wt2, bt2, out);

    // ---- layer 2: 64 -> 64, heads=1, residual, no relu + fused MLP heads ----
    qkvs_mfma_kernel<64><<<3125, 256, 0, stream>>>(hbuf0, Wp2,
        P[19], P[21], P[23], Qb, KVb, Sb);
    agg_kernel<1, true, false, true><<<12500, 256, 0, stream>>>(Qb, KVb, Sb,
        row_ptr, colb, P[25], P[26], hbuf0, hbuf1,
        Wr1, br1, Wr2, br2, Wt1, bt1, Wt2, bt2, out);
}